// Round 14
// baseline (326.862 us; speedup 1.0000x reference)
//
#include <hip/hip_runtime.h>
#include <hip/hip_bf16.h>
#include <math.h>

// Nq=20000, K=32, Cin=3, Fc=64, Co=64. Persistent blocks; 4 queries (128 rows)/iter.
// r13 kernel with doubled per-iteration work: Phase B runs as a NON-UNROLLED
// 2-trip loop (register reuse forced -> no r12-style spill), then ONE barrier,
// then 8 MFMA tiles. Barriers per query halved; residency still 4 blocks/CU
// (LDS 38.8KB). Register wall rules: (256,4), no state live across Phase D.
#define KNB 32
#define FC 64
#define CO 64
#define EPS 1e-5f
#define NBLOCKS 1000
#define CL 0.180336880095853f   // 0.125 * log2(e): softmax scale folded for exp2

typedef __attribute__((ext_vector_type(8))) short short8;   // 8 bf16 = 4 VGPRs
typedef __attribute__((ext_vector_type(4))) float floatx4;  // MFMA C/D
typedef __attribute__((ext_vector_type(2))) float float2v;  // v_pk_*_f32 operand

#if __has_builtin(__builtin_amdgcn_exp2f)
#define EXP2F(x) __builtin_amdgcn_exp2f(x)
#else
#define EXP2F(x) exp2f(x)
#endif
#if __has_builtin(__builtin_amdgcn_rcpf)
#define RCPF(x) __builtin_amdgcn_rcpf(x)
#else
#define RCPF(x) (1.f / (x))
#endif

// native packed f32->bf16 RNE (v_cvt_pk_bf16_f32): 1 inst / 2 values
__device__ __forceinline__ unsigned pk2(float a, float b) {    // a->lo, b->hi
    __hip_bfloat162 h = __float22bfloat162_rn(float2{a, b});
    unsigned u; __builtin_memcpy(&u, &h, 4); return u;
}
__device__ __forceinline__ unsigned pk2v(float2v v) { return pk2(v.x, v.y); }
__device__ __forceinline__ float lrelu(float x) { return fmaxf(x, 0.1f * x); }
__device__ __forceinline__ float2v fma2(float2v a, float2v b, float2v c) {
    return __builtin_elementwise_fma(a, b, c);      // v_pk_fma_f32
}
__device__ __forceinline__ float2v max2(float2v a, float2v b) {
    return __builtin_elementwise_max(a, b);         // v_pk_max_f32
}
__device__ __forceinline__ float2v lrelu2(float2v x) {
    return max2(x, 0.1f * x);
}

__global__ __launch_bounds__(256, 4) void GCT_61272003445298_kernel(
    const float* __restrict__ q_points,   // [Nq,3]
    const float* __restrict__ s_points,   // [Nq,3]
    const int*   __restrict__ neighb,     // [Nq,32]
    const float* __restrict__ feat,       // [Nq,64]
    const float* __restrict__ W_pos2,     // [64,3]
    const float* __restrict__ W_attn,     // [192,64]
    const float* __restrict__ W_res,      // [64,64]
    const float* __restrict__ bnq_g, const float* __restrict__ bnq_b,
    const float* __restrict__ bnq_m, const float* __restrict__ bnq_v,
    const float* __restrict__ bnp_g, const float* __restrict__ bnp_b,
    const float* __restrict__ bnp_m, const float* __restrict__ bnp_v,
    const float* __restrict__ bn1_g, const float* __restrict__ bn1_b,
    const float* __restrict__ bn1_m, const float* __restrict__ bn1_v,
    const float* __restrict__ bnr_g, const float* __restrict__ bnr_b,
    const float* __restrict__ bnr_m, const float* __restrict__ bnr_v,
    const float* __restrict__ zp,         // 4KB zero page in d_ws (shadow row)
    float* __restrict__ out, int Nq)
{
    const int t = threadIdx.x;
    const int wv = t >> 6;
    const int lane = t & 63;
    // consumer mapping
    const int cc = lane & 15, quad = lane >> 4;
    const int o = wv * 16 + cc;                 // output channel
    // producer mapping (conflict-free LDS stores): thread = (qB, kg, fqB)
    const int qB  = t >> 7;                     // query parity within group
    const int kg  = lane >> 3;                  // 0..7 -> rows kg*4..+3
    const int fqB = (((t >> 6) & 1) << 3) + (lane & 7);   // 0..15, 4 f each

    // rows m = qidx*32 + k (qidx 0..3); pitch 72 shorts = 144 B
    __shared__ __align__(16) short sA1[128 * 72];  // softmax probs, bf16
    __shared__ __align__(16) short sA2[128 * 72];  // gathered yg, bf16
    __shared__ __align__(16) float sXvC[3][128];   // x_v, component-major
    __shared__ __align__(16) float sWp2[192];      // CL * W_pos2
    __shared__ __align__(16) float sQs[64], sQb[64];  // bnq folded

    // ---------------- one-time init ----------------
    if (t < 192) sWp2[t] = CL * W_pos2[t];
    if (t < 64) {
        float sc = bnq_g[t] * rsqrtf(bnq_v[t] + EPS);
        sQs[t] = sc; sQb[t] = bnq_b[t] - bnq_m[t] * sc;
    }
    const float ps0 = bnp_g[0] * rsqrtf(bnp_v[0] + EPS);
    const float ps1 = bnp_g[1] * rsqrtf(bnp_v[1] + EPS);
    const float ps2 = bnp_g[2] * rsqrtf(bnp_v[2] + EPS);
    const float pb0 = bnp_b[0] - bnp_m[0] * ps0;
    const float pb1 = bnp_b[1] - bnp_m[1] * ps1;
    const float pb2 = bnp_b[2] - bnp_m[2] * ps2;
    // epilogue BN (per-lane o): scales folded into bW below; biases kept live
    const float e1s = bn1_g[o] * rsqrtf(bn1_v[o] + EPS);
    const float e1b = bn1_b[o] - bn1_m[o] * e1s;
    const float ers = bnr_g[o] * rsqrtf(bnr_v[o] + EPS);
    const float erb = bnr_b[o] - bnr_m[o] * ers;

    // persistent bf16 weights, BN scale pre-folded (ty<3: *e1s, ty3: *ers)
    short8 bW[4][2];
    #pragma unroll
    for (int ty = 0; ty < 4; ++ty) {
        const float* wrow = (ty < 3) ? (W_attn + (long)(o * 3 + ty) * FC)
                                     : (W_res  + (long)o * FC);
        const float sc = (ty < 3) ? e1s : ers;
        #pragma unroll
        for (int ks = 0; ks < 2; ++ks) {
            int k0 = ks * 32 + quad * 8;
            float4 w0 = *(const float4*)(wrow + k0);
            float4 w1 = *(const float4*)(wrow + k0 + 4);
            uint4 pv;
            pv.x = pk2(w0.x * sc, w0.y * sc);
            pv.y = pk2(w0.z * sc, w0.w * sc);
            pv.z = pk2(w1.x * sc, w1.y * sc);
            pv.w = pk2(w1.z * sc, w1.w * sc);
            __builtin_memcpy(&bW[ty][ks], &pv, 16);
        }
    }
    __syncthreads();

    // persistent pos-weight slice, component-major pairs for pk-math
    float2v wpa[3], wpb[3];
    {
        const float* w = &sWp2[fqB * 12];
        wpa[0] = (float2v){w[0], w[3]};  wpa[1] = (float2v){w[1], w[4]};
        wpa[2] = (float2v){w[2], w[5]};
        wpb[0] = (float2v){w[6], w[9]};  wpb[1] = (float2v){w[7], w[10]};
        wpb[2] = (float2v){w[8], w[11]};
    }
    const float4 qs4 = *(const float4*)&sQs[fqB * 4];
    const float4 qb4 = *(const float4*)&sQb[fqB * 4];
    const float4* __restrict__ feat4 = (const float4*)feat;

    const int ng = (Nq + 3) >> 2;            // groups of 4 queries
    for (int p = blockIdx.x; p < ng; p += NBLOCKS) {
        const int nbase = 4 * p;

        // ------- Phase B x2 (NON-UNROLLED: forces register reuse, no spill) ---
        #pragma unroll 1
        for (int qq = 0; qq < 2; ++qq) {
            const int qidx = qq * 2 + qB;
            long nn = nbase + qidx;
            if (nn >= Nq) nn = Nq - 1;       // clamped dummy; store guarded later
            const float q0 = q_points[nn * 3 + 0];
            const float q1 = q_points[nn * 3 + 1];
            const float q2 = q_points[nn * 3 + 2];
            const float pp0 = lrelu(fmaf(s_points[nn * 3 + 0], ps0, pb0));
            const float pp1 = lrelu(fmaf(s_points[nn * 3 + 1], ps1, pb1));
            const float pp2 = lrelu(fmaf(s_points[nn * 3 + 2], ps2, pb2));
            const int4 idx4 = *(const int4*)(neighb + nn * KNB + kg * 4);

            // xqc (pk): CL*lrelu(bnq(feat)) + pos0 . wp
            float2v xqcA, xqcB;
            {
                const float4 fx = feat4[(int)(nn * 16) + fqB];
                float2v xqA = lrelu2(fma2((float2v){fx.x, fx.y},
                                          (float2v){qs4.x, qs4.y},
                                          (float2v){qb4.x, qb4.y}));
                float2v xqB = lrelu2(fma2((float2v){fx.z, fx.w},
                                          (float2v){qs4.z, qs4.w},
                                          (float2v){qb4.z, qb4.w}));
                const float2v v0 = (float2v){pp0, pp0};
                const float2v v1 = (float2v){pp1, pp1};
                const float2v v2 = (float2v){pp2, pp2};
                xqcA = fma2(v0, wpa[0], fma2(v1, wpa[1], fma2(v2, wpa[2], CL * xqA)));
                xqcB = fma2(v0, wpb[0], fma2(v1, wpb[1], fma2(v2, wpb[2], CL * xqB)));
            }

            const int rowB = qidx * 32 + kg * 4;
            short* a1b = &sA1[rowB * 72 + fqB * 4];
            short* a2b = &sA2[rowB * 72 + fqB * 4];
            float2v evA[4], evB[4];
            float2v sumA = (float2v){0.f, 0.f}, sumB = (float2v){0.f, 0.f};
            #pragma unroll
            for (int j = 0; j < 4; ++j) {
                const int idx = ((const int*)&idx4)[j];
                const bool valid = (idx < Nq);      // idx==Nq -> zero page
                const float* fb = valid ? (feat + (long)idx * FC) : zp;
                const float* sb = valid ? (s_points + (long)idx * 3) : zp;
                const float4 y = *(const float4*)(fb + fqB * 4);
                uint2 pk; pk.x = pk2(y.x, y.y); pk.y = pk2(y.z, y.w);
                *(uint2*)(a2b + j * 72) = pk;
                const float xv0 = sb[0] - q0;
                const float xv1 = sb[1] - q1;
                const float xv2 = sb[2] - q2;
                if (fqB == 0) {
                    const int row = rowB + j;
                    sXvC[0][row] = xv0; sXvC[1][row] = xv1; sXvC[2][row] = xv2;
                }
                const float2v m0 = (float2v){-xv0, -xv0};
                const float2v m1 = (float2v){-xv1, -xv1};
                const float2v m2 = (float2v){-xv2, -xv2};
                float2v lA = fma2((float2v){y.x, y.y}, (float2v){-CL, -CL}, xqcA);
                lA = fma2(m0, wpa[0], lA); lA = fma2(m1, wpa[1], lA); lA = fma2(m2, wpa[2], lA);
                float2v lB = fma2((float2v){y.z, y.w}, (float2v){-CL, -CL}, xqcB);
                lB = fma2(m0, wpb[0], lB); lB = fma2(m1, wpb[1], lB); lB = fma2(m2, wpb[2], lB);
                evA[j] = (float2v){EXP2F(lA.x), EXP2F(lA.y)};
                evB[j] = (float2v){EXP2F(lB.x), EXP2F(lB.y)};
                sumA = sumA + evA[j];
                sumB = sumB + evB[j];
            }
            // softmax k-sum over the 8 kg lanes (lane bits 3..5)
            float s0 = sumA.x, s1 = sumA.y, s2 = sumB.x, s3 = sumB.y;
            s0 += __shfl_xor(s0, 8); s0 += __shfl_xor(s0, 16); s0 += __shfl_xor(s0, 32);
            s1 += __shfl_xor(s1, 8); s1 += __shfl_xor(s1, 16); s1 += __shfl_xor(s1, 32);
            s2 += __shfl_xor(s2, 8); s2 += __shfl_xor(s2, 16); s2 += __shfl_xor(s2, 32);
            s3 += __shfl_xor(s3, 8); s3 += __shfl_xor(s3, 16); s3 += __shfl_xor(s3, 32);
            const float2v invA = (float2v){RCPF(s0), RCPF(s1)};
            const float2v invB = (float2v){RCPF(s2), RCPF(s3)};
            #pragma unroll
            for (int j = 0; j < 4; ++j) {
                uint2 pw;
                pw.x = pk2v(evA[j] * invA);
                pw.y = pk2v(evB[j] * invB);
                *(uint2*)(a1b + j * 72) = pw;
            }
        }
        __syncthreads();

        // ------- Phase D: 8 MFMA tiles (4 queries) + pk epilogue --------------
        const float2v e1b2 = (float2v){e1b, e1b};
        float2v mp[4];
        #pragma unroll
        for (int qi = 0; qi < 4; ++qi) mp[qi] = (float2v){-1e30f, -1e30f};
        #pragma unroll
        for (int mt = 0; mt < 8; ++mt) {
            floatx4 acc[4];
            #pragma unroll
            for (int ty = 0; ty < 4; ++ty) acc[ty] = (floatx4){0.f, 0.f, 0.f, 0.f};
            const int r0 = mt * 16 + cc;               // A row m = lane&15
            #pragma unroll
            for (int ks = 0; ks < 2; ++ks) {
                const int kof = ks * 32 + quad * 8;    // A k-slice = quad*8+j
                short8 a1 = *(const short8*)(sA1 + r0 * 72 + kof);
                short8 a2 = *(const short8*)(sA2 + r0 * 72 + kof);
                acc[0] = __builtin_amdgcn_mfma_f32_16x16x32_bf16(a1, bW[0][ks], acc[0], 0, 0, 0);
                acc[1] = __builtin_amdgcn_mfma_f32_16x16x32_bf16(a1, bW[1][ks], acc[1], 0, 0, 0);
                acc[2] = __builtin_amdgcn_mfma_f32_16x16x32_bf16(a1, bW[2][ks], acc[2], 0, 0, 0);
                acc[3] = __builtin_amdgcn_mfma_f32_16x16x32_bf16(a2, bW[3][ks], acc[3], 0, 0, 0);
            }
            // C/D: col = lane&15, row = quad*4 + reg. Reg-pairs -> v_pk math.
            #pragma unroll
            for (int rp = 0; rp < 2; ++rp) {
                const int r = mt * 16 + quad * 4 + rp * 2;
                const float2v xv0 = *(const float2v*)&sXvC[0][r];
                const float2v xv1 = *(const float2v*)&sXvC[1][r];
                const float2v xv2 = *(const float2v*)&sXvC[2][r];
                const float2v a0 = (float2v){acc[0][rp*2], acc[0][rp*2+1]};
                const float2v a1 = (float2v){acc[1][rp*2], acc[1][rp*2+1]};
                const float2v a2 = (float2v){acc[2][rp*2], acc[2][rp*2+1]};
                const float2v a3 = (float2v){acc[3][rp*2], acc[3][rp*2+1]};
                float2v y2 = a0 * xv0;
                y2 = fma2(a1, xv1, y2);
                y2 = fma2(a2, xv2, y2);
                const float2v v2 = lrelu2(y2 + e1b2) + a3;
                mp[mt >> 1] = max2(mp[mt >> 1], v2);
            }
        }
        #pragma unroll
        for (int qi = 0; qi < 4; ++qi) {
            float mr = fmaxf(mp[qi].x, mp[qi].y);
            mr = fmaxf(mr, __shfl_xor(mr, 16));
            mr = fmaxf(mr, __shfl_xor(mr, 32));
            const long n = nbase + qi;
            if (lane < 16 && n < Nq) out[n * CO + o] = lrelu(mr + erb);
        }
        __syncthreads();   // protect sA1/sA2/sXvC before next iteration
    }
}

extern "C" void kernel_launch(void* const* d_in, const int* in_sizes, int n_in,
                              void* d_out, int out_size, void* d_ws, size_t ws_size,
                              hipStream_t stream) {
    const float* q_points = (const float*)d_in[0];
    const float* s_points = (const float*)d_in[1];
    const int*   neighb   = (const int*)  d_in[2];
    const float* feat     = (const float*)d_in[3];
    const float* W_pos2   = (const float*)d_in[4];
    const float* W_attn   = (const float*)d_in[5];
    const float* W_res    = (const float*)d_in[6];
    const float* bnq_g = (const float*)d_in[7];
    const float* bnq_b = (const float*)d_in[8];
    const float* bnq_m = (const float*)d_in[9];
    const float* bnq_v = (const float*)d_in[10];
    const float* bnp_g = (const float*)d_in[11];
    const float* bnp_b = (const float*)d_in[12];
    const float* bnp_m = (const float*)d_in[13];
    const float* bnp_v = (const float*)d_in[14];
    const float* bn1_g = (const float*)d_in[15];
    const float* bn1_b = (const float*)d_in[16];
    const float* bn1_m = (const float*)d_in[17];
    const float* bn1_v = (const float*)d_in[18];
    const float* bnr_g = (const float*)d_in[19];
    const float* bnr_b = (const float*)d_in[20];
    const float* bnr_m = (const float*)d_in[21];
    const float* bnr_v = (const float*)d_in[22];
    float* out = (float*)d_out;

    int Nq = in_sizes[0] / 3;               // 20000

    // zero page for shadow-row gathers; d_ws re-poisoned before every timed call
    size_t zn = ws_size < 4096 ? ws_size : (size_t)4096;
    hipMemsetAsync(d_ws, 0, zn, stream);

    hipLaunchKernelGGL(GCT_61272003445298_kernel,
                       dim3(NBLOCKS), dim3(256), 0, stream,
                       q_points, s_points, neighb, feat, W_pos2, W_attn, W_res,
                       bnq_g, bnq_b, bnq_m, bnq_v,
                       bnp_g, bnp_b, bnp_m, bnp_v,
                       bn1_g, bn1_b, bn1_m, bn1_v,
                       bnr_g, bnr_b, bnr_m, bnr_v,
                       (const float*)d_ws, out, Nq);
}

// Round 15
// 160.171 us; speedup vs baseline: 2.0407x; 2.0407x over previous
//
#include <hip/hip_runtime.h>
#include <hip/hip_bf16.h>
#include <math.h>

// Nq=20000, K=32, Cin=3, Fc=64, Co=64. Persistent blocks; 2 queries (64 rows)/iter.
// CHAMPION (r10, 65.0us dispatch): r6 skeleton (single LDS buffer, 2 barriers/iter)
// + VALU diet (native v_cvt_pk_bf16_f32, v_pk_fma_f32 logits, BN folded into
// persistent weights, deferred epilogue bias/lrelu past k-max).
// Register wall (measured r4/r9/r12/r14): the (256,4) budget is exactly full
// with bW(32 VGPR)+acc(16)+Phase B working set. ANY added live state across
// Phase D spills to scratch (FETCH/WRITE balloon). Occupancy is capped at
// 4 waves/SIMD regardless of grid (r11). Do not restructure; this is the
// fixed point of the design.
#define KNB 32
#define FC 64
#define CO 64
#define EPS 1e-5f
#define NBLOCKS 1024
#define CL 0.180336880095853f   // 0.125 * log2(e): softmax scale folded for exp2

typedef __attribute__((ext_vector_type(8))) short short8;   // 8 bf16 = 4 VGPRs
typedef __attribute__((ext_vector_type(4))) float floatx4;  // MFMA C/D
typedef __attribute__((ext_vector_type(2))) float float2v;  // v_pk_*_f32 operand

#if __has_builtin(__builtin_amdgcn_exp2f)
#define EXP2F(x) __builtin_amdgcn_exp2f(x)
#else
#define EXP2F(x) exp2f(x)
#endif
#if __has_builtin(__builtin_amdgcn_rcpf)
#define RCPF(x) __builtin_amdgcn_rcpf(x)
#else
#define RCPF(x) (1.f / (x))
#endif

// native packed f32->bf16 RNE (v_cvt_pk_bf16_f32): 1 inst / 2 values
__device__ __forceinline__ unsigned pk2(float a, float b) {    // a->lo, b->hi
    __hip_bfloat162 h = __float22bfloat162_rn(float2{a, b});
    unsigned u; __builtin_memcpy(&u, &h, 4); return u;
}
__device__ __forceinline__ unsigned pk2v(float2v v) { return pk2(v.x, v.y); }
__device__ __forceinline__ float lrelu(float x) { return fmaxf(x, 0.1f * x); }
__device__ __forceinline__ float2v fma2(float2v a, float2v b, float2v c) {
    return __builtin_elementwise_fma(a, b, c);      // v_pk_fma_f32
}
__device__ __forceinline__ float2v lrelu2(float2v x) {
    return __builtin_elementwise_max(x, 0.1f * x);
}

__global__ __launch_bounds__(256, 4) void GCT_61272003445298_kernel(
    const float* __restrict__ q_points,   // [Nq,3]
    const float* __restrict__ s_points,   // [Nq,3]
    const int*   __restrict__ neighb,     // [Nq,32]
    const float* __restrict__ feat,       // [Nq,64]
    const float* __restrict__ W_pos2,     // [64,3]
    const float* __restrict__ W_attn,     // [192,64]
    const float* __restrict__ W_res,      // [64,64]
    const float* __restrict__ bnq_g, const float* __restrict__ bnq_b,
    const float* __restrict__ bnq_m, const float* __restrict__ bnq_v,
    const float* __restrict__ bnp_g, const float* __restrict__ bnp_b,
    const float* __restrict__ bnp_m, const float* __restrict__ bnp_v,
    const float* __restrict__ bn1_g, const float* __restrict__ bn1_b,
    const float* __restrict__ bn1_m, const float* __restrict__ bn1_v,
    const float* __restrict__ bnr_g, const float* __restrict__ bnr_b,
    const float* __restrict__ bnr_m, const float* __restrict__ bnr_v,
    float* __restrict__ out, int Nq)
{
    const int t = threadIdx.x;
    const int wv = t >> 6;
    const int lane = t & 63;
    // consumer mapping
    const int cc = lane & 15, quad = lane >> 4;
    const int o = wv * 16 + cc;                 // output channel
    // producer mapping (r6, conflict-free stores): thread = (qB, kg, fqB)
    const int qB  = t >> 7;                     // query within pair
    const int kg  = lane >> 3;                  // 0..7 -> rows kg*4..+3
    const int fqB = (((t >> 6) & 1) << 3) + (lane & 7);   // 0..15, 4 f each

    // rows m = q*32 + k; pitch 72 shorts = 144 B (16B-aligned b128)
    __shared__ __align__(16) short sA1[64 * 72];   // softmax probs, bf16
    __shared__ __align__(16) short sA2[64 * 72];   // gathered yg, bf16
    __shared__ float sXv[64][4];                   // x_v per row
    __shared__ __align__(16) float sWp2[192];      // CL * W_pos2
    __shared__ __align__(16) float sQs[64], sQb[64];  // bnq folded

    // ---------------- one-time init ----------------
    if (t < 192) sWp2[t] = CL * W_pos2[t];
    if (t < 64) {
        float sc = bnq_g[t] * rsqrtf(bnq_v[t] + EPS);
        sQs[t] = sc; sQb[t] = bnq_b[t] - bnq_m[t] * sc;
    }
    const float ps0 = bnp_g[0] * rsqrtf(bnp_v[0] + EPS);
    const float ps1 = bnp_g[1] * rsqrtf(bnp_v[1] + EPS);
    const float ps2 = bnp_g[2] * rsqrtf(bnp_v[2] + EPS);
    const float pb0 = bnp_b[0] - bnp_m[0] * ps0;
    const float pb1 = bnp_b[1] - bnp_m[1] * ps1;
    const float pb2 = bnp_b[2] - bnp_m[2] * ps2;
    // epilogue BN (per-lane o): scales folded into bW below; biases kept live
    const float e1s = bn1_g[o] * rsqrtf(bn1_v[o] + EPS);
    const float e1b = bn1_b[o] - bn1_m[o] * e1s;
    const float ers = bnr_g[o] * rsqrtf(bnr_v[o] + EPS);
    const float erb = bnr_b[o] - bnr_m[o] * ers;

    // persistent bf16 weights, BN scale pre-folded (ty<3: *e1s, ty3: *ers)
    short8 bW[4][2];
    #pragma unroll
    for (int ty = 0; ty < 4; ++ty) {
        const float* wrow = (ty < 3) ? (W_attn + (long)(o * 3 + ty) * FC)
                                     : (W_res  + (long)o * FC);
        const float sc = (ty < 3) ? e1s : ers;
        #pragma unroll
        for (int ks = 0; ks < 2; ++ks) {
            int k0 = ks * 32 + quad * 8;
            float4 w0 = *(const float4*)(wrow + k0);
            float4 w1 = *(const float4*)(wrow + k0 + 4);
            uint4 pv;
            pv.x = pk2(w0.x * sc, w0.y * sc);
            pv.y = pk2(w0.z * sc, w0.w * sc);
            pv.z = pk2(w1.x * sc, w1.y * sc);
            pv.w = pk2(w1.z * sc, w1.w * sc);
            __builtin_memcpy(&bW[ty][ks], &pv, 16);
        }
    }
    __syncthreads();

    // persistent pos-weight slice, component-major pairs for pk-math:
    // wpa[i] = {w(f0,i), w(f1,i)}, wpb[i] = {w(f2,i), w(f3,i)}  (CL-prescaled)
    float2v wpa[3], wpb[3];
    {
        const float* w = &sWp2[fqB * 12];
        wpa[0] = (float2v){w[0], w[3]};  wpa[1] = (float2v){w[1], w[4]};
        wpa[2] = (float2v){w[2], w[5]};
        wpb[0] = (float2v){w[6], w[9]};  wpb[1] = (float2v){w[7], w[10]};
        wpb[2] = (float2v){w[8], w[11]};
    }
    const float4 qs4 = *(const float4*)&sQs[fqB * 4];
    const float4 qb4 = *(const float4*)&sQb[fqB * 4];
    const float4* __restrict__ feat4 = (const float4*)feat;

    const int npair = (Nq + 1) >> 1;
    for (int p = blockIdx.x; p < npair; p += NBLOCKS) {
        const long n0 = 2L * p;
        long n1 = n0 + 1;
        const bool has1 = (n1 < Nq);
        if (!has1) n1 = n0;
        const long nn = qB ? n1 : n0;

        // ---------------- Phase B: gather + logits + softmax, one pass --------
        const float nq0 = -q_points[nn * 3 + 0];
        const float nq1 = -q_points[nn * 3 + 1];
        const float nq2 = -q_points[nn * 3 + 2];
        const float pp0 = lrelu(fmaf(s_points[nn * 3 + 0], ps0, pb0));
        const float pp1 = lrelu(fmaf(s_points[nn * 3 + 1], ps1, pb1));
        const float pp2 = lrelu(fmaf(s_points[nn * 3 + 2], ps2, pb2));
        const int4 idx4 = *(const int4*)(neighb + nn * KNB + kg * 4);

        // xqc (pk): CL*lrelu(bnq(feat)) + pos0 . wp   for this thread's 4 f
        float2v xqcA, xqcB;
        {
            const float4 fx = feat4[(int)(nn * 16) + fqB];
            float2v xqA = lrelu2(fma2((float2v){fx.x, fx.y},
                                      (float2v){qs4.x, qs4.y},
                                      (float2v){qb4.x, qb4.y}));
            float2v xqB = lrelu2(fma2((float2v){fx.z, fx.w},
                                      (float2v){qs4.z, qs4.w},
                                      (float2v){qb4.z, qb4.w}));
            const float2v v0 = (float2v){pp0, pp0};
            const float2v v1 = (float2v){pp1, pp1};
            const float2v v2 = (float2v){pp2, pp2};
            xqcA = fma2(v0, wpa[0], fma2(v1, wpa[1], fma2(v2, wpa[2], CL * xqA)));
            xqcB = fma2(v0, wpb[0], fma2(v1, wpb[1], fma2(v2, wpb[2], CL * xqB)));
        }

        short* a1b = &sA1[(qB * 32 + kg * 4) * 72 + fqB * 4];
        short* a2b = &sA2[(qB * 32 + kg * 4) * 72 + fqB * 4];
        float2v evA[4], evB[4];
        float2v sumA = (float2v){0.f, 0.f}, sumB = (float2v){0.f, 0.f};
        #pragma unroll
        for (int j = 0; j < 4; ++j) {
            const int idx = ((const int*)&idx4)[j];
            const float sel = (idx < Nq) ? 1.f : 0.f;   // idx==Nq -> shadow zeros
            const int idc = (idx < Nq) ? idx : 0;
            float4 y = feat4[idc * 16 + fqB];
            y.x *= sel; y.y *= sel; y.z *= sel; y.w *= sel;
            uint2 pk; pk.x = pk2(y.x, y.y); pk.y = pk2(y.z, y.w);
            *(uint2*)(a2b + j * 72) = pk;
            const float xv0 = fmaf(s_points[idc * 3 + 0], sel, nq0);
            const float xv1 = fmaf(s_points[idc * 3 + 1], sel, nq1);
            const float xv2 = fmaf(s_points[idc * 3 + 2], sel, nq2);
            if (fqB == 0) {
                float4 xvv = {xv0, xv1, xv2, 0.f};
                *(float4*)&sXv[qB * 32 + kg * 4 + j][0] = xvv;
            }
            const float2v m0 = (float2v){-xv0, -xv0};
            const float2v m1 = (float2v){-xv1, -xv1};
            const float2v m2 = (float2v){-xv2, -xv2};
            float2v lA = fma2((float2v){y.x, y.y}, (float2v){-CL, -CL}, xqcA);
            lA = fma2(m0, wpa[0], lA); lA = fma2(m1, wpa[1], lA); lA = fma2(m2, wpa[2], lA);
            float2v lB = fma2((float2v){y.z, y.w}, (float2v){-CL, -CL}, xqcB);
            lB = fma2(m0, wpb[0], lB); lB = fma2(m1, wpb[1], lB); lB = fma2(m2, wpb[2], lB);
            evA[j] = (float2v){EXP2F(lA.x), EXP2F(lA.y)};
            evB[j] = (float2v){EXP2F(lB.x), EXP2F(lB.y)};
            sumA = sumA + evA[j];
            sumB = sumB + evB[j];
        }
        // softmax k-sum over the 8 kg lanes (lane bits 3..5)
        float s0 = sumA.x, s1 = sumA.y, s2 = sumB.x, s3 = sumB.y;
        s0 += __shfl_xor(s0, 8); s0 += __shfl_xor(s0, 16); s0 += __shfl_xor(s0, 32);
        s1 += __shfl_xor(s1, 8); s1 += __shfl_xor(s1, 16); s1 += __shfl_xor(s1, 32);
        s2 += __shfl_xor(s2, 8); s2 += __shfl_xor(s2, 16); s2 += __shfl_xor(s2, 32);
        s3 += __shfl_xor(s3, 8); s3 += __shfl_xor(s3, 16); s3 += __shfl_xor(s3, 32);
        const float2v invA = (float2v){RCPF(s0), RCPF(s1)};
        const float2v invB = (float2v){RCPF(s2), RCPF(s3)};
        #pragma unroll
        for (int j = 0; j < 4; ++j) {
            uint2 pw;
            pw.x = pk2v(evA[j] * invA);       // v_pk_mul + v_cvt_pk_bf16
            pw.y = pk2v(evB[j] * invB);
            *(uint2*)(a1b + j * 72) = pw;
        }
        __syncthreads();

        // ---------------- Phase D: MFMA + fused epilogue per 16-row tile -------
        float m0r = -1e30f, m1r = -1e30f;
        #pragma unroll
        for (int mt = 0; mt < 4; ++mt) {
            floatx4 acc[4];
            #pragma unroll
            for (int ty = 0; ty < 4; ++ty) acc[ty] = (floatx4){0.f, 0.f, 0.f, 0.f};
            const int r0 = mt * 16 + cc;               // A row m = lane&15
            #pragma unroll
            for (int ks = 0; ks < 2; ++ks) {
                const int kof = ks * 32 + quad * 8;    // A k-slice = quad*8+j
                short8 a1 = *(const short8*)(sA1 + r0 * 72 + kof);
                short8 a2 = *(const short8*)(sA2 + r0 * 72 + kof);
                acc[0] = __builtin_amdgcn_mfma_f32_16x16x32_bf16(a1, bW[0][ks], acc[0], 0, 0, 0);
                acc[1] = __builtin_amdgcn_mfma_f32_16x16x32_bf16(a1, bW[1][ks], acc[1], 0, 0, 0);
                acc[2] = __builtin_amdgcn_mfma_f32_16x16x32_bf16(a1, bW[2][ks], acc[2], 0, 0, 0);
                acc[3] = __builtin_amdgcn_mfma_f32_16x16x32_bf16(a2, bW[3][ks], acc[3], 0, 0, 0);
            }
            // C/D: col = lane&15, row = quad*4 + reg. BN scales live in bW;
            // +erb and outer lrelu deferred past k-max (lrelu monotone).
            #pragma unroll
            for (int reg = 0; reg < 4; ++reg) {
                const int r = mt * 16 + quad * 4 + reg;
                float4 xv = *(const float4*)&sXv[r][0];
                float y = acc[0][reg] * xv.x + acc[1][reg] * xv.y + acc[2][reg] * xv.z;
                float v = lrelu(y + e1b) + acc[3][reg];
                if (mt < 2) m0r = fmaxf(m0r, v); else m1r = fmaxf(m1r, v);
            }
        }
        m0r = fmaxf(m0r, __shfl_xor(m0r, 16));
        m0r = fmaxf(m0r, __shfl_xor(m0r, 32));
        m1r = fmaxf(m1r, __shfl_xor(m1r, 16));
        m1r = fmaxf(m1r, __shfl_xor(m1r, 32));
        if (lane < 16) {
            out[n0 * CO + o] = lrelu(m0r + erb);
            if (has1) out[n1 * CO + o] = lrelu(m1r + erb);
        }
        __syncthreads();   // protect sA1/sA2/sXv before next iteration
    }
}

extern "C" void kernel_launch(void* const* d_in, const int* in_sizes, int n_in,
                              void* d_out, int out_size, void* d_ws, size_t ws_size,
                              hipStream_t stream) {
    const float* q_points = (const float*)d_in[0];
    const float* s_points = (const float*)d_in[1];
    const int*   neighb   = (const int*)  d_in[2];
    const float* feat     = (const float*)d_in[3];
    const float* W_pos2   = (const float*)d_in[4];
    const float* W_attn   = (const float*)d_in[5];
    const float* W_res    = (const float*)d_in[6];
    const float* bnq_g = (const float*)d_in[7];
    const float* bnq_b = (const float*)d_in[8];
    const float* bnq_m = (const float*)d_in[9];
    const float* bnq_v = (const float*)d_in[10];
    const float* bnp_g = (const float*)d_in[11];
    const float* bnp_b = (const float*)d_in[12];
    const float* bnp_m = (const float*)d_in[13];
    const float* bnp_v = (const float*)d_in[14];
    const float* bn1_g = (const float*)d_in[15];
    const float* bn1_b = (const float*)d_in[16];
    const float* bn1_m = (const float*)d_in[17];
    const float* bn1_v = (const float*)d_in[18];
    const float* bnr_g = (const float*)d_in[19];
    const float* bnr_b = (const float*)d_in[20];
    const float* bnr_m = (const float*)d_in[21];
    const float* bnr_v = (const float*)d_in[22];
    float* out = (float*)d_out;

    int Nq = in_sizes[0] / 3;               // 20000

    hipLaunchKernelGGL(GCT_61272003445298_kernel,
                       dim3(NBLOCKS), dim3(256), 0, stream,
                       q_points, s_points, neighb, feat, W_pos2, W_attn, W_res,
                       bnq_g, bnq_b, bnq_m, bnq_v,
                       bnp_g, bnp_b, bnp_m, bnp_v,
                       bn1_g, bn1_b, bn1_m, bn1_v,
                       bnr_g, bnr_b, bnr_m, bnr_v,
                       out, Nq);
}